// Round 4
// baseline (301.212 us; speedup 1.0000x reference)
//
#include <hip/hip_runtime.h>
#include <hip/hip_bf16.h>
#include <cstdint>

#define SEQ 192

typedef float f32x4 __attribute__((ext_vector_type(4)));
typedef __bf16 bf16;
typedef __bf16 bf16x8 __attribute__((ext_vector_type(8)));
typedef __bf16 bf16x4 __attribute__((ext_vector_type(4)));

#define MFMA_BF16(a, b, c) __builtin_amdgcn_mfma_f32_16x16x32_bf16(a, b, c, 0, 0, 0)

// =================== K1: weight prep + WVt transpose + LayerNorm ===================
__global__ __launch_bounds__(256) void k1_prep(
    const float* __restrict__ x, const float* __restrict__ ln_w, const float* __restrict__ ln_b,
    const float* __restrict__ Wab, const float* __restrict__ Wout, const float* __restrict__ WK,
    const float* __restrict__ WV, bf16* __restrict__ xn_bf, bf16* __restrict__ Wab_bf,
    bf16* __restrict__ Wout_bf, bf16* __restrict__ WK2t, bf16* __restrict__ WVt) {
  int bid = blockIdx.x, tid = threadIdx.x;
  if (bid < 14336) {
    long idx = (long)bid * 256 + tid;
    if (idx < 1310720) { Wab_bf[idx] = (bf16)Wab[idx]; return; }
    idx -= 1310720;
    if (idx < 262144) { Wout_bf[idx] = (bf16)Wout[idx]; return; }
    idx -= 262144;
    int o = (int)idx;  // < 2097152 ; WK2t[(i*64+j)*512 + h*64+k] = WK[h][i][j][k]
    int k = o & 63, hh = (o >> 6) & 7, j = (o >> 9) & 63, i = o >> 15;
    WK2t[o] = (bf16)WK[(((size_t)(hh * 64 + i) * 64 + j) * 64) + k];
    return;
  }
  bid -= 14336;
  if (bid < 512) {  // WVt[h][(g*64+f)*64 + h'] = WV[h][h'][g][f]
    int g = bid & 63, hh = bid >> 6;
    __shared__ float ld[64 * 65];
    int f = tid & 63, r4 = tid >> 6;
#pragma unroll
    for (int it = 0; it < 16; it++) {
      int hp = it * 4 + r4;
      ld[hp * 65 + f] = WV[(((size_t)(hh * 64 + hp) * 64 + g) * 64) + f];
    }
    __syncthreads();
    int hp2 = tid & 63;
#pragma unroll
    for (int it = 0; it < 16; it++) {
      int ff = it * 4 + r4;
      WVt[(size_t)hh * 262144 + (size_t)(g * 64 + ff) * 64 + hp2] = (bf16)ld[hp2 * 65 + ff];
    }
    return;
  }
  bid -= 512;
  {  // LayerNorm row r = bid
    int r = bid;
    const float* xr = x + (size_t)r * 512;
    float v0 = xr[tid], v1 = xr[tid + 256];
    float s = v0 + v1, s2 = v0 * v0 + v1 * v1;
#pragma unroll
    for (int off = 32; off > 0; off >>= 1) {
      s += __shfl_down(s, off);
      s2 += __shfl_down(s2, off);
    }
    __shared__ float redS[4], redS2[4];
    int wave = tid >> 6, lane = tid & 63;
    if (lane == 0) { redS[wave] = s; redS2[wave] = s2; }
    __syncthreads();
    float S = redS[0] + redS[1] + redS[2] + redS[3];
    float S2 = redS2[0] + redS2[1] + redS2[2] + redS2[3];
    float mean = S * (1.0f / 512.0f);
    float var = S2 * (1.0f / 512.0f) - mean * mean;
    float rstd = rsqrtf(var + 1e-5f);
    bf16* xnr = xn_bf + (size_t)r * 512;
    xnr[tid] = (bf16)((v0 - mean) * rstd * ln_w[tid] + ln_b[tid]);
    xnr[tid + 256] = (bf16)((v1 - mean) * rstd * ln_w[tid + 256] + ln_b[tid + 256]);
  }
}

// =================== LDS-free bf16 MFMA GEMM core (C = A @ Bt^T) ===================
// MODE 0: f32 row-major + bias ; MODE 1: bf16 row-major ; MODE 2: s2 layout
// [m>>6][n][m&63] bf16x4 ; MODE 3: tT layout C1[(n&63)*12288 + m*64 + (n>>6)] bf16
template <int MODE, bool HAS_BIAS>
__device__ __forceinline__ void gemm_body(const bf16* __restrict__ A, const bf16* __restrict__ Bt,
                                          float* __restrict__ C0, bf16* __restrict__ C1,
                                          const float* __restrict__ bias, int N, int K,
                                          int nb, int mb, int tid) {
  int n0 = nb * 64, m0 = mb * 64;
  int wave = tid >> 6, lane = tid & 63;
  int lq = lane >> 4, l16 = lane & 15;
  const bf16* Ap = A + (size_t)(m0 + wave * 16 + l16) * K;
  f32x4 acc[4];
#pragma unroll
  for (int nt = 0; nt < 4; nt++) acc[nt] = (f32x4){0.f, 0.f, 0.f, 0.f};
  for (int k0 = 0; k0 < K; k0 += 32) {
    bf16x8 af = *(const bf16x8*)(Ap + k0 + lq * 8);
#pragma unroll
    for (int nt = 0; nt < 4; nt++) {
      bf16x8 bv = *(const bf16x8*)(Bt + (size_t)(n0 + nt * 16 + l16) * K + k0 + lq * 8);
      acc[nt] = MFMA_BF16(af, bv, acc[nt]);
    }
  }
  int cm = m0 + wave * 16 + lq * 4;
#pragma unroll
  for (int nt = 0; nt < 4; nt++) {
    int n = n0 + nt * 16 + l16;
    if constexpr (MODE == 0) {
      float bv = HAS_BIAS ? bias[n] : 0.f;
#pragma unroll
      for (int rg = 0; rg < 4; rg++) C0[(size_t)(cm + rg) * N + n] = acc[nt][rg] + bv;
    } else if constexpr (MODE == 1) {
#pragma unroll
      for (int rg = 0; rg < 4; rg++) C1[(size_t)(cm + rg) * N + n] = (bf16)acc[nt][rg];
    } else if constexpr (MODE == 2) {
      int r = cm >> 6, i0 = cm & 63;
      bf16x4 pk = {(bf16)acc[nt][0], (bf16)acc[nt][1], (bf16)acc[nt][2], (bf16)acc[nt][3]};
      *(bf16x4*)(C1 + (size_t)r * 12288 + (size_t)n * 64 + i0) = pk;
    } else {  // MODE 3: tT
      int g = n >> 6, f = n & 63;
#pragma unroll
      for (int rg = 0; rg < 4; rg++)
        C1[(size_t)f * 12288 + (size_t)(cm + rg) * 64 + g] = (bf16)acc[nt][rg];
    }
  }
}

// =================== K2: proj GEMM + slice epilogue ===================
// proj = xn @ Wab^T + b (f32) ; also a_bf[h][p][i], c_bf[p][512], d_bf[h][p][i]
__global__ __launch_bounds__(256) void k2_proj(
    const bf16* __restrict__ xn_bf, const bf16* __restrict__ Wab_bf,
    const float* __restrict__ b_abcde, float* __restrict__ proj, bf16* __restrict__ a_bf,
    bf16* __restrict__ c_bf, bf16* __restrict__ d_bf) {
  int bid = blockIdx.x, tid = threadIdx.x;
  int nb = bid % 40, mb = bid / 40;
  int n0 = nb * 64, m0 = mb * 64;
  int wave = tid >> 6, lane = tid & 63;
  int lq = lane >> 4, l16 = lane & 15;
  const bf16* Ap = xn_bf + (size_t)(m0 + wave * 16 + l16) * 512;
  f32x4 acc[4];
#pragma unroll
  for (int nt = 0; nt < 4; nt++) acc[nt] = (f32x4){0.f, 0.f, 0.f, 0.f};
  for (int k0 = 0; k0 < 512; k0 += 32) {
    bf16x8 af = *(const bf16x8*)(Ap + k0 + lq * 8);
#pragma unroll
    for (int nt = 0; nt < 4; nt++) {
      bf16x8 bv = *(const bf16x8*)(Wab_bf + (size_t)(n0 + nt * 16 + l16) * 512 + k0 + lq * 8);
      acc[nt] = MFMA_BF16(af, bv, acc[nt]);
    }
  }
  int cm = m0 + wave * 16 + lq * 4;
#pragma unroll
  for (int nt = 0; nt < 4; nt++) {
    int n = n0 + nt * 16 + l16;
    int chunk = n >> 9, hcol = (n >> 6) & 7, i = n & 63;
#pragma unroll
    for (int rg = 0; rg < 4; rg++) {
      int m = cm + rg;
      float v = acc[nt][rg] + b_abcde[n];
      proj[(size_t)m * 2560 + n] = v;
      bf16 bv = (bf16)v;
      if (chunk == 0) a_bf[((size_t)hcol * SEQ + m) * 64 + i] = bv;
      else if (chunk == 2) c_bf[(size_t)m * 512 + (n - 1024)] = bv;
      else if (chunk == 3) d_bf[((size_t)hcol * SEQ + m) * 64 + i] = bv;
    }
  }
}

// =================== K3: step1 GEMM + t GEMM + eT/ecum + bsum (role-fused) ===================
__global__ __launch_bounds__(256) void k3_mid(
    const bf16* __restrict__ c_bf, const bf16* __restrict__ WK2t, bf16* __restrict__ s1bf,
    const bf16* __restrict__ d_bf, const bf16* __restrict__ WVt, bf16* __restrict__ tT_bf,
    const float* __restrict__ proj, bf16* __restrict__ eT_bf, float* __restrict__ ecum,
    bf16* __restrict__ bsum_bf) {
  __shared__ float el[192 * 65];
  int bid = blockIdx.x, tid = threadIdx.x;
  if (bid < 192) {  // step1: [192 x 4096] = c @ WK2t^T, K=512 -> bf16 row-major
    gemm_body<1, false>(c_bf, WK2t, nullptr, s1bf, nullptr, 4096, 512, bid % 64, bid / 64, tid);
    return;
  }
  bid -= 192;
  if (bid < 1536) {  // t[h]: [192 x 4096] = d_h @ WVt[h]^T, K=64 -> tT_bf[h][f][p*64+g]
    int h = bid / 192, rem = bid % 192;
    gemm_body<3, false>(d_bf + (size_t)h * 12288, WVt + (size_t)h * 262144, nullptr,
                        tT_bf + (size_t)h * 786432, nullptr, 4096, 64, rem % 64, rem / 64, tid);
    return;
  }
  bid -= 1536;
  if (bid < 8) {  // per-head: eT transpose + ecum prefix scan
    int h = bid;
    for (int idx = tid; idx < 12288; idx += 256) {
      int p = idx >> 6, g = idx & 63;
      el[p * 65 + g] = proj[(size_t)p * 2560 + 2048 + h * 64 + g];
    }
    __syncthreads();
    for (int idx = tid; idx < 12288; idx += 256) {
      int g = idx / 192, q = idx - g * 192;
      eT_bf[((size_t)h * 64 + g) * SEQ + q] = (bf16)el[q * 65 + g];
    }
    if (tid < 64) {
      float run = 0.f;
      for (int p = 0; p < SEQ; p++) {
        run += el[p * 65 + tid];
        ecum[(size_t)h * 12288 + p * 64 + tid] = run;
      }
    }
    return;
  }
  bid -= 8;
  {  // bsum[q][j] = sum_h b[q,h,j] -> bf16 ; 3 blocks x 64 q
    int j = tid & 63, qg = tid >> 6;
#pragma unroll
    for (int qi = 0; qi < 16; qi++) {
      int q = bid * 64 + qg * 16 + qi;
      float s = 0.f;
#pragma unroll
      for (int hh = 0; hh < 8; hh++) s += proj[(size_t)q * 2560 + 512 + hh * 64 + j];
      bsum_bf[q * 64 + j] = (bf16)s;
    }
  }
}

// =================== K4: step2 GEMM -> s2bf[r][q][i] ===================
__global__ __launch_bounds__(256) void k4_step2(const bf16* __restrict__ s1bf,
                                                const bf16* __restrict__ bsum_bf,
                                                bf16* __restrict__ s2bf) {
  int bid = blockIdx.x;
  gemm_body<2, false>(s1bf, bsum_bf, nullptr, s2bf, nullptr, 192, 64, bid % 3, bid / 3,
                      threadIdx.x);
}

// =================== K5: fused scores+exp+ew(+ecum)+zGEMM+L-normalize ===================
// grid (8 h, 24 rb); 512 thr = 8 waves; wave w owns r = rb*8+w.
// Per ptile: per-wave scores->w (16x32 LDS chunk buf) -> ew MFMA (f32) -> +ecum ->
// bf16 into ewb LDS (rows 0-7 = r's, rows 8-15 zero) -> block-coop z MFMA K-split.
__global__ __launch_bounds__(512) void k5_attnz(
    const bf16* __restrict__ a_bf, const bf16* __restrict__ s2bf,
    const bf16* __restrict__ eT_bf, const float* __restrict__ ecum,
    const bf16* __restrict__ tT_bf, bf16* __restrict__ z_bf) {
  int h = blockIdx.x, rb = blockIdx.y;
  int tid = threadIdx.x, wave = tid >> 6, lane = tid & 63;
  int lq = lane >> 4, l16 = lane & 15;
  int r = rb * 8 + wave;
  __shared__ bf16 wch[8][16 * 40];   // per-wave w chunk [p16][k32 pad40]
  __shared__ bf16 ewb[16 * 1032];    // [r16][k1024 pad1032]; rows 8-15 stay zero
  __shared__ float zred[8][8][64];
  __shared__ float Ls[8];

  const bf16* ah = a_bf + (size_t)h * 12288;
  const bf16* s2r = s2bf + (size_t)r * 12288;
  const bf16* eh = eT_bf + (size_t)h * 12288;
  const bf16* th = tT_bf + (size_t)h * 786432;
  const float* ech = ecum + (size_t)h * 12288;

  // zero pad rows of ewb (ordered vs first z-read by the in-loop barrier)
  for (int idx = tid; idx < 8 * 1032; idx += 512) ewb[8 * 1032 + idx] = (bf16)0.f;

  f32x4 zacc[4];
#pragma unroll
  for (int nt = 0; nt < 4; nt++) zacc[nt] = (f32x4){0.f, 0.f, 0.f, 0.f};
  float lpart = 0.f;
  bf16* mywch = &wch[wave][0];

  for (int pt = 0; pt < 12; pt++) {
    bf16x8 af0 = *(const bf16x8*)(ah + (pt * 16 + l16) * 64 + lq * 8);
    bf16x8 af1 = *(const bf16x8*)(ah + (pt * 16 + l16) * 64 + 32 + lq * 8);
    f32x4 ewacc[4];
#pragma unroll
    for (int nt = 0; nt < 4; nt++) ewacc[nt] = (f32x4){0.f, 0.f, 0.f, 0.f};
    int c0 = (pt * 16 + 1) >> 5;  // first not-fully-masked 32-chunk
    for (int c = c0; c < 6; c++) {
#pragma unroll
      for (int sub = 0; sub < 2; sub++) {
        int q = c * 32 + sub * 16 + l16;
        bf16x8 b0 = *(const bf16x8*)(s2r + q * 64 + lq * 8);
        bf16x8 b1 = *(const bf16x8*)(s2r + q * 64 + 32 + lq * 8);
        f32x4 sv = (f32x4){0.f, 0.f, 0.f, 0.f};
        sv = MFMA_BF16(af0, b0, sv);
        sv = MFMA_BF16(af1, b1, sv);
        int p0 = pt * 16 + lq * 4;
#pragma unroll
        for (int rg = 0; rg < 4; rg++) {
          int p = p0 + rg;
          float wv = (q > p) ? __expf(sv[rg] * 0.015625f) : 0.f;
          lpart += wv;
          mywch[(lq * 4 + rg) * 40 + sub * 16 + l16] = (bf16)wv;
        }
      }
      bf16x8 wf = *(const bf16x8*)(mywch + l16 * 40 + lq * 8);
#pragma unroll
      for (int nt = 0; nt < 4; nt++) {
        bf16x8 ef = *(const bf16x8*)(eh + (nt * 16 + l16) * SEQ + c * 32 + lq * 8);
        ewacc[nt] = MFMA_BF16(wf, ef, ewacc[nt]);
      }
    }
    // ew' = ew + ecum (folds the masked-mass Vm into the z GEMM), store bf16 to ewb
#pragma unroll
    for (int nt = 0; nt < 4; nt++)
#pragma unroll
      for (int rg = 0; rg < 4; rg++) {
        float v = ewacc[nt][rg] + ech[(pt * 16 + lq * 4 + rg) * 64 + nt * 16 + l16];
        ewb[wave * 1032 + (lq * 4 + rg) * 64 + nt * 16 + l16] = (bf16)v;
      }
    __syncthreads();
    // z GEMM: K-split, wave handles 4 of 32 k-chunks of this ptile's 1024 k-values
#pragma unroll
    for (int kc2 = 0; kc2 < 4; kc2++) {
      int kk = (wave * 4 + kc2) * 32;
      bf16x8 afz = *(const bf16x8*)(ewb + l16 * 1032 + kk + lq * 8);
#pragma unroll
      for (int nt = 0; nt < 4; nt++) {
        bf16x8 tf = *(const bf16x8*)(th + (size_t)(nt * 16 + l16) * 12288 + pt * 1024 + kk + lq * 8);
        zacc[nt] = MFMA_BF16(afz, tf, zacc[nt]);
      }
    }
    __syncthreads();  // ewb reused next ptile
  }
#pragma unroll
  for (int off = 32; off > 0; off >>= 1) lpart += __shfl_down(lpart, off);
  if (lane == 0) Ls[wave] = lpart;
  if (lq < 2) {
#pragma unroll
    for (int nt = 0; nt < 4; nt++)
#pragma unroll
      for (int rg = 0; rg < 4; rg++) zred[wave][lq * 4 + rg][nt * 16 + l16] = zacc[nt][rg];
  }
  __syncthreads();
  int rr = tid >> 6, f = tid & 63;
  float ssum = 0.f;
#pragma unroll
  for (int wv = 0; wv < 8; wv++) ssum += zred[wv][rr][f];
  float L = Ls[rr] + 18528.0f;  // 18528 masked (p>=q) entries with weight exactly 1.0f
  z_bf[(size_t)(rb * 8 + rr) * 512 + h * 64 + f] = (bf16)(ssum / L);
}

// =================== K6: out = z @ Wout^T + b_out ===================
__global__ __launch_bounds__(256) void k6_out(const bf16* __restrict__ z_bf,
                                              const bf16* __restrict__ Wout_bf,
                                              const float* __restrict__ b_out,
                                              float* __restrict__ out) {
  int bid = blockIdx.x;
  gemm_body<0, true>(z_bf, Wout_bf, out, nullptr, b_out, 512, 512, bid & 7, bid >> 3,
                     threadIdx.x);
}

// =================== workspace layout (f32 units) ===================
static const size_t OFF_PROJ = 0;         // f32 491520
static const size_t OFF_ECUM = 491520;    // f32 98304
static const size_t OFF_XN = 589824;      // bf16 98304 -> 49152
static const size_t OFF_WAB = 638976;     // bf16 1310720 -> 655360
static const size_t OFF_WOUT = 1294336;   // bf16 262144 -> 131072
static const size_t OFF_WK2T = 1425408;   // bf16 2097152 -> 1048576
static const size_t OFF_WVT = 2473984;    // bf16 2097152 -> 1048576
static const size_t OFF_A = 3522560;      // bf16 98304 -> 49152
static const size_t OFF_C = 3571712;      // 49152
static const size_t OFF_D = 3620864;      // 49152
static const size_t OFF_ET = 3670016;     // 49152
static const size_t OFF_BSUM = 3719168;   // bf16 12288 -> 6144
static const size_t OFF_S1 = 3725312;     // bf16 786432 -> 393216
static const size_t OFF_S2 = 4118528;     // bf16 2359296 -> 1179648
static const size_t OFF_TT = 5298176;     // bf16 6291456 -> 3145728
static const size_t OFF_Z = 8443904;      // bf16 98304 -> 49152
// TOTAL = 8493056 f32 = 34 MB

extern "C" void kernel_launch(void* const* d_in, const int* in_sizes, int n_in,
                              void* d_out, int out_size, void* d_ws, size_t ws_size,
                              hipStream_t stream) {
  (void)in_sizes; (void)n_in; (void)out_size; (void)ws_size;
  const float* x = (const float*)d_in[0];
  const float* ln_w = (const float*)d_in[1];
  const float* ln_b = (const float*)d_in[2];
  const float* W_abcde = (const float*)d_in[3];
  const float* b_abcde = (const float*)d_in[4];
  const float* W_K = (const float*)d_in[5];
  const float* W_V = (const float*)d_in[6];
  const float* W_out = (const float*)d_in[7];
  const float* b_out = (const float*)d_in[8];
  float* out = (float*)d_out;
  float* ws = (float*)d_ws;

  float* proj = ws + OFF_PROJ;
  float* ecum = ws + OFF_ECUM;
  bf16* xn_bf = (bf16*)(ws + OFF_XN);
  bf16* Wab_bf = (bf16*)(ws + OFF_WAB);
  bf16* Wout_bf = (bf16*)(ws + OFF_WOUT);
  bf16* WK2t = (bf16*)(ws + OFF_WK2T);
  bf16* WVt = (bf16*)(ws + OFF_WVT);
  bf16* a_bf = (bf16*)(ws + OFF_A);
  bf16* c_bf = (bf16*)(ws + OFF_C);
  bf16* d_bf = (bf16*)(ws + OFF_D);
  bf16* eT_bf = (bf16*)(ws + OFF_ET);
  bf16* bsum_bf = (bf16*)(ws + OFF_BSUM);
  bf16* s1bf = (bf16*)(ws + OFF_S1);
  bf16* s2bf = (bf16*)(ws + OFF_S2);
  bf16* tT_bf = (bf16*)(ws + OFF_TT);
  bf16* z_bf = (bf16*)(ws + OFF_Z);

  k1_prep<<<15040, 256, 0, stream>>>(x, ln_w, ln_b, W_abcde, W_out, W_K, W_V, xn_bf, Wab_bf,
                                     Wout_bf, WK2t, WVt);
  k2_proj<<<120, 256, 0, stream>>>(xn_bf, Wab_bf, b_abcde, proj, a_bf, c_bf, d_bf);
  k3_mid<<<1739, 256, 0, stream>>>(c_bf, WK2t, s1bf, d_bf, WVt, tT_bf, proj, eT_bf, ecum,
                                   bsum_bf);
  k4_step2<<<576, 256, 0, stream>>>(s1bf, bsum_bf, s2bf);
  k5_attnz<<<dim3(8, 24), 512, 0, stream>>>(a_bf, s2bf, eT_bf, ecum, tT_bf, z_bf);
  k6_out<<<24, 256, 0, stream>>>(z_bf, Wout_bf, b_out, out);
}

// Round 5
// 281.305 us; speedup vs baseline: 1.0708x; 1.0708x over previous
//
#include <hip/hip_runtime.h>
#include <hip/hip_bf16.h>
#include <cstdint>

#define SEQ 192

typedef float f32x4 __attribute__((ext_vector_type(4)));
typedef __bf16 bf16;
typedef __bf16 bf16x8 __attribute__((ext_vector_type(8)));
typedef __bf16 bf16x4 __attribute__((ext_vector_type(4)));

#define MFMA_BF16(a, b, c) __builtin_amdgcn_mfma_f32_16x16x32_bf16(a, b, c, 0, 0, 0)

// =================== K1: weight prep + WVt transpose + LayerNorm ===================
__global__ __launch_bounds__(256) void k1_prep(
    const float* __restrict__ x, const float* __restrict__ ln_w, const float* __restrict__ ln_b,
    const float* __restrict__ Wab, const float* __restrict__ Wout, const float* __restrict__ WK,
    const float* __restrict__ WV, bf16* __restrict__ xn_bf, bf16* __restrict__ Wab_bf,
    bf16* __restrict__ Wout_bf, bf16* __restrict__ WK2t, bf16* __restrict__ WVt) {
  int bid = blockIdx.x, tid = threadIdx.x;
  if (bid < 14336) {
    long idx = (long)bid * 256 + tid;
    if (idx < 1310720) { Wab_bf[idx] = (bf16)Wab[idx]; return; }
    idx -= 1310720;
    if (idx < 262144) { Wout_bf[idx] = (bf16)Wout[idx]; return; }
    idx -= 262144;
    int o = (int)idx;  // < 2097152 ; WK2t[(i*64+j)*512 + h*64+k] = WK[h][i][j][k]
    int k = o & 63, hh = (o >> 6) & 7, j = (o >> 9) & 63, i = o >> 15;
    WK2t[o] = (bf16)WK[(((size_t)(hh * 64 + i) * 64 + j) * 64) + k];
    return;
  }
  bid -= 14336;
  if (bid < 512) {  // WVt[h][(g*64+f)*64 + h'] = WV[h][h'][g][f]
    int g = bid & 63, hh = bid >> 6;
    __shared__ float ld[64 * 65];
    int f = tid & 63, r4 = tid >> 6;
#pragma unroll
    for (int it = 0; it < 16; it++) {
      int hp = it * 4 + r4;
      ld[hp * 65 + f] = WV[(((size_t)(hh * 64 + hp) * 64 + g) * 64) + f];
    }
    __syncthreads();
    int hp2 = tid & 63;
#pragma unroll
    for (int it = 0; it < 16; it++) {
      int ff = it * 4 + r4;
      WVt[(size_t)hh * 262144 + (size_t)(g * 64 + ff) * 64 + hp2] = (bf16)ld[hp2 * 65 + ff];
    }
    return;
  }
  bid -= 512;
  {  // LayerNorm row r = bid
    int r = bid;
    const float* xr = x + (size_t)r * 512;
    float v0 = xr[tid], v1 = xr[tid + 256];
    float s = v0 + v1, s2 = v0 * v0 + v1 * v1;
#pragma unroll
    for (int off = 32; off > 0; off >>= 1) {
      s += __shfl_down(s, off);
      s2 += __shfl_down(s2, off);
    }
    __shared__ float redS[4], redS2[4];
    int wave = tid >> 6, lane = tid & 63;
    if (lane == 0) { redS[wave] = s; redS2[wave] = s2; }
    __syncthreads();
    float S = redS[0] + redS[1] + redS[2] + redS[3];
    float S2 = redS2[0] + redS2[1] + redS2[2] + redS2[3];
    float mean = S * (1.0f / 512.0f);
    float var = S2 * (1.0f / 512.0f) - mean * mean;
    float rstd = rsqrtf(var + 1e-5f);
    bf16* xnr = xn_bf + (size_t)r * 512;
    xnr[tid] = (bf16)((v0 - mean) * rstd * ln_w[tid] + ln_b[tid]);
    xnr[tid + 256] = (bf16)((v1 - mean) * rstd * ln_w[tid + 256] + ln_b[tid + 256]);
  }
}

// =================== LDS-free bf16 MFMA GEMM core (C = A @ Bt^T) ===================
// MODE 0: f32 row-major + bias ; MODE 1: bf16 row-major ; MODE 2: s2 layout
// [m>>6][n][m&63] bf16x4 ; MODE 3: tT layout C1[(n&63)*12288 + m*64 + (n>>6)] bf16
template <int MODE, bool HAS_BIAS>
__device__ __forceinline__ void gemm_body(const bf16* __restrict__ A, const bf16* __restrict__ Bt,
                                          float* __restrict__ C0, bf16* __restrict__ C1,
                                          const float* __restrict__ bias, int N, int K,
                                          int nb, int mb, int tid) {
  int n0 = nb * 64, m0 = mb * 64;
  int wave = tid >> 6, lane = tid & 63;
  int lq = lane >> 4, l16 = lane & 15;
  const bf16* Ap = A + (size_t)(m0 + wave * 16 + l16) * K;
  f32x4 acc[4];
#pragma unroll
  for (int nt = 0; nt < 4; nt++) acc[nt] = (f32x4){0.f, 0.f, 0.f, 0.f};
  for (int k0 = 0; k0 < K; k0 += 32) {
    bf16x8 af = *(const bf16x8*)(Ap + k0 + lq * 8);
#pragma unroll
    for (int nt = 0; nt < 4; nt++) {
      bf16x8 bv = *(const bf16x8*)(Bt + (size_t)(n0 + nt * 16 + l16) * K + k0 + lq * 8);
      acc[nt] = MFMA_BF16(af, bv, acc[nt]);
    }
  }
  int cm = m0 + wave * 16 + lq * 4;
#pragma unroll
  for (int nt = 0; nt < 4; nt++) {
    int n = n0 + nt * 16 + l16;
    if constexpr (MODE == 0) {
      float bv = HAS_BIAS ? bias[n] : 0.f;
#pragma unroll
      for (int rg = 0; rg < 4; rg++) C0[(size_t)(cm + rg) * N + n] = acc[nt][rg] + bv;
    } else if constexpr (MODE == 1) {
#pragma unroll
      for (int rg = 0; rg < 4; rg++) C1[(size_t)(cm + rg) * N + n] = (bf16)acc[nt][rg];
    } else if constexpr (MODE == 2) {
      int r = cm >> 6, i0 = cm & 63;
      bf16x4 pk = {(bf16)acc[nt][0], (bf16)acc[nt][1], (bf16)acc[nt][2], (bf16)acc[nt][3]};
      *(bf16x4*)(C1 + (size_t)r * 12288 + (size_t)n * 64 + i0) = pk;
    } else {  // MODE 3: tT
      int g = n >> 6, f = n & 63;
#pragma unroll
      for (int rg = 0; rg < 4; rg++)
        C1[(size_t)f * 12288 + (size_t)(cm + rg) * 64 + g] = (bf16)acc[nt][rg];
    }
  }
}

// =================== K2: proj GEMM + slice epilogue ===================
__global__ __launch_bounds__(256) void k2_proj(
    const bf16* __restrict__ xn_bf, const bf16* __restrict__ Wab_bf,
    const float* __restrict__ b_abcde, float* __restrict__ proj, bf16* __restrict__ a_bf,
    bf16* __restrict__ c_bf, bf16* __restrict__ d_bf) {
  int bid = blockIdx.x, tid = threadIdx.x;
  int nb = bid % 40, mb = bid / 40;
  int n0 = nb * 64, m0 = mb * 64;
  int wave = tid >> 6, lane = tid & 63;
  int lq = lane >> 4, l16 = lane & 15;
  const bf16* Ap = xn_bf + (size_t)(m0 + wave * 16 + l16) * 512;
  f32x4 acc[4];
#pragma unroll
  for (int nt = 0; nt < 4; nt++) acc[nt] = (f32x4){0.f, 0.f, 0.f, 0.f};
  for (int k0 = 0; k0 < 512; k0 += 32) {
    bf16x8 af = *(const bf16x8*)(Ap + k0 + lq * 8);
#pragma unroll
    for (int nt = 0; nt < 4; nt++) {
      bf16x8 bv = *(const bf16x8*)(Wab_bf + (size_t)(n0 + nt * 16 + l16) * 512 + k0 + lq * 8);
      acc[nt] = MFMA_BF16(af, bv, acc[nt]);
    }
  }
  int cm = m0 + wave * 16 + lq * 4;
#pragma unroll
  for (int nt = 0; nt < 4; nt++) {
    int n = n0 + nt * 16 + l16;
    int chunk = n >> 9, hcol = (n >> 6) & 7, i = n & 63;
#pragma unroll
    for (int rg = 0; rg < 4; rg++) {
      int m = cm + rg;
      float v = acc[nt][rg] + b_abcde[n];
      proj[(size_t)m * 2560 + n] = v;
      bf16 bv = (bf16)v;
      if (chunk == 0) a_bf[((size_t)hcol * SEQ + m) * 64 + i] = bv;
      else if (chunk == 2) c_bf[(size_t)m * 512 + (n - 1024)] = bv;
      else if (chunk == 3) d_bf[((size_t)hcol * SEQ + m) * 64 + i] = bv;
    }
  }
}

// =================== K3: step1 GEMM + t GEMM + eT/ecum + bsum (role-fused) ===================
__global__ __launch_bounds__(256) void k3_mid(
    const bf16* __restrict__ c_bf, const bf16* __restrict__ WK2t, bf16* __restrict__ s1bf,
    const bf16* __restrict__ d_bf, const bf16* __restrict__ WVt, bf16* __restrict__ tT_bf,
    const float* __restrict__ proj, bf16* __restrict__ eT_bf, float* __restrict__ ecum,
    bf16* __restrict__ bsum_bf) {
  __shared__ float el[64 * 65];  // 16.6 KB (chunked e transpose)
  int bid = blockIdx.x, tid = threadIdx.x;
  if (bid < 192) {  // step1: [192 x 4096] = c @ WK2t^T, K=512 -> bf16 row-major
    gemm_body<1, false>(c_bf, WK2t, nullptr, s1bf, nullptr, 4096, 512, bid % 64, bid / 64, tid);
    return;
  }
  bid -= 192;
  if (bid < 1536) {  // t[h]: [192 x 4096] = d_h @ WVt[h]^T, K=64 -> tT_bf[h][f][p*64+g]
    int h = bid / 192, rem = bid % 192;
    gemm_body<3, false>(d_bf + (size_t)h * 12288, WVt + (size_t)h * 262144, nullptr,
                        tT_bf + (size_t)h * 786432, nullptr, 4096, 64, rem % 64, rem / 64, tid);
    return;
  }
  bid -= 1536;
  if (bid < 8) {  // per-head: eT transpose + ecum prefix scan, 64-row chunks with carry
    int h = bid;
    float carry = 0.f;
    for (int ch = 0; ch < 3; ch++) {
      int pbase = ch * 64;
      for (int idx = tid; idx < 4096; idx += 256) {
        int pl = idx >> 6, g = idx & 63;
        el[pl * 65 + g] = proj[(size_t)(pbase + pl) * 2560 + 2048 + h * 64 + g];
      }
      __syncthreads();
      for (int idx = tid; idx < 4096; idx += 256) {
        int g = idx >> 6, ql = idx & 63;
        eT_bf[((size_t)h * 64 + g) * SEQ + pbase + ql] = (bf16)el[ql * 65 + g];
      }
      if (tid < 64) {
        float run = carry;
        for (int pl = 0; pl < 64; pl++) {
          run += el[pl * 65 + tid];
          ecum[(size_t)h * 12288 + (pbase + pl) * 64 + tid] = run;
        }
        carry = run;
      }
      __syncthreads();
    }
    return;
  }
  bid -= 8;
  {  // bsum[q][j] = sum_h b[q,h,j] -> bf16 ; 3 blocks x 64 q
    int j = tid & 63, qg = tid >> 6;
#pragma unroll
    for (int qi = 0; qi < 16; qi++) {
      int q = bid * 64 + qg * 16 + qi;
      float s = 0.f;
#pragma unroll
      for (int hh = 0; hh < 8; hh++) s += proj[(size_t)q * 2560 + 512 + hh * 64 + j];
      bsum_bf[q * 64 + j] = (bf16)s;
    }
  }
}

// =================== K4: step2 GEMM -> s2bf[r][q][i] ===================
__global__ __launch_bounds__(256) void k4_step2(const bf16* __restrict__ s1bf,
                                                const bf16* __restrict__ bsum_bf,
                                                bf16* __restrict__ s2bf) {
  int bid = blockIdx.x;
  gemm_body<2, false>(s1bf, bsum_bf, nullptr, s2bf, nullptr, 192, 64, bid % 3, bid / 3,
                      threadIdx.x);
}

// =================== K5: scores+exp+ew(+ecum) per (r,h), small-LDS ===================
// 4 waves; wave w owns p-tiles {w, w+4, 11-w} (active-chunk counts 11/11/10/10).
// Per (c-chunk of 32 q): scores MFMA -> exp -> per-wave 16x32 LDS buffer -> ew MFMA.
// ew' = ew + ecum (folds masked mass Vm into the z GEMM). No block barriers in loop.
__global__ __launch_bounds__(256) void k5_attn(
    const bf16* __restrict__ a_bf, const bf16* __restrict__ s2bf,
    const bf16* __restrict__ eT_bf, const float* __restrict__ ecum,
    bf16* __restrict__ ew_bf, float* __restrict__ Lsum) {
  int r = blockIdx.x, h = blockIdx.y;
  int tid = threadIdx.x, wave = tid >> 6, lane = tid & 63;
  int lq = lane >> 4, l16 = lane & 15;
  __shared__ __align__(16) bf16 wch[4][16 * 40];  // 5.1 KB total
  __shared__ float redL[4];
  int pt[3] = {wave, wave + 4, 11 - wave};

  const bf16* ah = a_bf + (size_t)h * 12288;
  const bf16* s2r = s2bf + (size_t)r * 12288;
  const bf16* eh = eT_bf + (size_t)h * 12288;
  const float* ech = ecum + (size_t)h * 12288;
  bf16* myw = &wch[wave][0];

  bf16x8 afr[3][2];
#pragma unroll
  for (int mt = 0; mt < 3; mt++)
#pragma unroll
    for (int kc = 0; kc < 2; kc++)
      afr[mt][kc] = *(const bf16x8*)(ah + (pt[mt] * 16 + l16) * 64 + kc * 32 + lq * 8);

  f32x4 ewacc[3][4];
#pragma unroll
  for (int mt = 0; mt < 3; mt++)
#pragma unroll
    for (int nt = 0; nt < 4; nt++) ewacc[mt][nt] = (f32x4){0.f, 0.f, 0.f, 0.f};
  float lpart = 0.f;

  for (int c = 0; c < 6; c++) {
    if (c * 32 + 31 <= wave * 16) continue;  // all 3 p-tiles fully masked for this wave
    bf16x8 efr[4];
#pragma unroll
    for (int nt = 0; nt < 4; nt++)
      efr[nt] = *(const bf16x8*)(eh + (nt * 16 + l16) * SEQ + c * 32 + lq * 8);
    bf16x8 bq0[2], bq1[2];
#pragma unroll
    for (int sub = 0; sub < 2; sub++) {
      int q = c * 32 + sub * 16 + l16;
      bq0[sub] = *(const bf16x8*)(s2r + q * 64 + lq * 8);
      bq1[sub] = *(const bf16x8*)(s2r + q * 64 + 32 + lq * 8);
    }
#pragma unroll
    for (int mt = 0; mt < 3; mt++) {
      int ptile = pt[mt];
      if (c * 32 + 31 <= ptile * 16) continue;  // fully masked 16x32 chunk -> zero contrib
#pragma unroll
      for (int sub = 0; sub < 2; sub++) {
        if (c * 32 + sub * 16 + 15 <= ptile * 16) {  // sub fully masked: zero-fill
#pragma unroll
          for (int rg = 0; rg < 4; rg++) myw[(lq * 4 + rg) * 40 + sub * 16 + l16] = (bf16)0.f;
          continue;
        }
        f32x4 sv = (f32x4){0.f, 0.f, 0.f, 0.f};
        sv = MFMA_BF16(afr[mt][0], bq0[sub], sv);
        sv = MFMA_BF16(afr[mt][1], bq1[sub], sv);
        int q = c * 32 + sub * 16 + l16;
        int p0 = ptile * 16 + lq * 4;
#pragma unroll
        for (int rg = 0; rg < 4; rg++) {
          float wv = (q > p0 + rg) ? __expf(sv[rg] * 0.015625f) : 0.f;
          lpart += wv;
          myw[(lq * 4 + rg) * 40 + sub * 16 + l16] = (bf16)wv;
        }
      }
      bf16x8 wf = *(const bf16x8*)(myw + l16 * 40 + lq * 8);
#pragma unroll
      for (int nt = 0; nt < 4; nt++) ewacc[mt][nt] = MFMA_BF16(wf, efr[nt], ewacc[mt][nt]);
    }
  }

  bf16* ewout = ew_bf + ((size_t)h * SEQ + r) * 12288;
#pragma unroll
  for (int mt = 0; mt < 3; mt++)
#pragma unroll
    for (int nt = 0; nt < 4; nt++)
#pragma unroll
      for (int rg = 0; rg < 4; rg++) {
        int p = pt[mt] * 16 + lq * 4 + rg;
        int g = nt * 16 + l16;
        ewout[p * 64 + g] = (bf16)(ewacc[mt][nt][rg] + ech[p * 64 + g]);
      }

#pragma unroll
  for (int off = 32; off > 0; off >>= 1) lpart += __shfl_down(lpart, off);
  if (lane == 0) redL[wave] = lpart;
  __syncthreads();
  if (tid == 0) Lsum[h * SEQ + r] = redL[0] + redL[1] + redL[2] + redL[3];
}

// =================== K5b: z[r, h*64+f] = (ew'[h,r,:] @ tT[h,:,:]) / L ===================
// grid (8 h, 12 mtiles); 512 thr = 8 waves splitting K=12288 8 ways; LDS reduce + /L.
__global__ __launch_bounds__(512) void k5b_z(
    const bf16* __restrict__ ew_bf, const bf16* __restrict__ tT_bf,
    const float* __restrict__ Lsum, bf16* __restrict__ z_bf) {
  int h = blockIdx.x, mt = blockIdx.y;
  int tid = threadIdx.x, wave = tid >> 6, lane = tid & 63;
  int lq = lane >> 4, l16 = lane & 15;
  __shared__ float zred[8][16][66];  // 33.8 KB, padded
  const bf16* ewh = ew_bf + ((size_t)h * SEQ + mt * 16) * 12288;
  const bf16* th = tT_bf + (size_t)h * 786432;
  f32x4 acc[4];
#pragma unroll
  for (int nt = 0; nt < 4; nt++) acc[nt] = (f32x4){0.f, 0.f, 0.f, 0.f};
  for (int j = 0; j < 48; j++) {
    int kk = (wave * 48 + j) * 32 + lq * 8;
    bf16x8 af = *(const bf16x8*)(ewh + (size_t)l16 * 12288 + kk);
#pragma unroll
    for (int nt = 0; nt < 4; nt++) {
      bf16x8 tf = *(const bf16x8*)(th + (size_t)(nt * 16 + l16) * 12288 + kk);
      acc[nt] = MFMA_BF16(af, tf, acc[nt]);
    }
  }
#pragma unroll
  for (int nt = 0; nt < 4; nt++)
#pragma unroll
    for (int rg = 0; rg < 4; rg++) zred[wave][lq * 4 + rg][nt * 16 + l16] = acc[nt][rg];
  __syncthreads();
#pragma unroll
  for (int o = 0; o < 2; o++) {
    int idx = o * 512 + tid;  // 1024 outputs: [rloc 16][f 64]
    int rloc = idx >> 6, f = idx & 63;
    float s = 0.f;
#pragma unroll
    for (int wv = 0; wv < 8; wv++) s += zred[wv][rloc][f];
    int rr = mt * 16 + rloc;
    float L = Lsum[h * SEQ + rr] + 18528.0f;  // 18528 masked entries with weight 1.0f
    z_bf[(size_t)rr * 512 + h * 64 + f] = (bf16)(s / L);
  }
}

// =================== K6: out = z @ Wout^T + b_out ===================
__global__ __launch_bounds__(256) void k6_out(const bf16* __restrict__ z_bf,
                                              const bf16* __restrict__ Wout_bf,
                                              const float* __restrict__ b_out,
                                              float* __restrict__ out) {
  int bid = blockIdx.x;
  gemm_body<0, true>(z_bf, Wout_bf, out, nullptr, b_out, 512, 512, bid & 7, bid >> 3,
                     threadIdx.x);
}

// =================== workspace layout (f32 units) ===================
static const size_t OFF_PROJ = 0;         // f32 491520
static const size_t OFF_ECUM = 491520;    // f32 98304
static const size_t OFF_XN = 589824;      // bf16 98304 -> 49152
static const size_t OFF_WAB = 638976;     // bf16 1310720 -> 655360
static const size_t OFF_WOUT = 1294336;   // bf16 262144 -> 131072
static const size_t OFF_WK2T = 1425408;   // bf16 2097152 -> 1048576
static const size_t OFF_WVT = 2473984;    // bf16 2097152 -> 1048576
static const size_t OFF_A = 3522560;      // bf16 98304 -> 49152
static const size_t OFF_C = 3571712;      // 49152
static const size_t OFF_D = 3620864;      // 49152
static const size_t OFF_ET = 3670016;     // 49152
static const size_t OFF_BSUM = 3719168;   // bf16 12288 -> 6144
static const size_t OFF_S1 = 3725312;     // bf16 786432 -> 393216
static const size_t OFF_S2 = 4118528;     // bf16 2359296 -> 1179648
static const size_t OFF_TT = 5298176;     // bf16 6291456 -> 3145728
static const size_t OFF_Z = 8443904;      // bf16 98304 -> 49152
static const size_t OFF_EW = 8493056;     // bf16 18874368 -> 9437184
// TOTAL = 17930240 f32 = 71.7 MB

extern "C" void kernel_launch(void* const* d_in, const int* in_sizes, int n_in,
                              void* d_out, int out_size, void* d_ws, size_t ws_size,
                              hipStream_t stream) {
  (void)in_sizes; (void)n_in; (void)out_size; (void)ws_size;
  const float* x = (const float*)d_in[0];
  const float* ln_w = (const float*)d_in[1];
  const float* ln_b = (const float*)d_in[2];
  const float* W_abcde = (const float*)d_in[3];
  const float* b_abcde = (const float*)d_in[4];
  const float* W_K = (const float*)d_in[5];
  const float* W_V = (const float*)d_in[6];
  const float* W_out = (const float*)d_in[7];
  const float* b_out = (const float*)d_in[8];
  float* out = (float*)d_out;
  float* ws = (float*)d_ws;

  float* proj = ws + OFF_PROJ;
  float* ecum = ws + OFF_ECUM;
  bf16* xn_bf = (bf16*)(ws + OFF_XN);
  bf16* Wab_bf = (bf16*)(ws + OFF_WAB);
  bf16* Wout_bf = (bf16*)(ws + OFF_WOUT);
  bf16* WK2t = (bf16*)(ws + OFF_WK2T);
  bf16* WVt = (bf16*)(ws + OFF_WVT);
  bf16* a_bf = (bf16*)(ws + OFF_A);
  bf16* c_bf = (bf16*)(ws + OFF_C);
  bf16* d_bf = (bf16*)(ws + OFF_D);
  bf16* eT_bf = (bf16*)(ws + OFF_ET);
  bf16* bsum_bf = (bf16*)(ws + OFF_BSUM);
  bf16* s1bf = (bf16*)(ws + OFF_S1);
  bf16* s2bf = (bf16*)(ws + OFF_S2);
  bf16* tT_bf = (bf16*)(ws + OFF_TT);
  bf16* z_bf = (bf16*)(ws + OFF_Z);
  bf16* ew_bf = (bf16*)(ws + OFF_EW);
  float* Lsum = ws + OFF_Z + 49152;  // reuse: put Lsum after z (z uses 49152 of its region)

  // Lsum needs its own space: carve 1536 floats from the end of EW region is unsafe;
  // simplest: place it in the gap after OFF_Z block (z only needs 49152 f32 units).
  // OFF_Z region allocated 49152; Lsum lives at ws + 17930240 (beyond EW).
  Lsum = ws + 17930240;

  k1_prep<<<15040, 256, 0, stream>>>(x, ln_w, ln_b, W_abcde, W_out, W_K, W_V, xn_bf, Wab_bf,
                                     Wout_bf, WK2t, WVt);
  k2_proj<<<120, 256, 0, stream>>>(xn_bf, Wab_bf, b_abcde, proj, a_bf, c_bf, d_bf);
  k3_mid<<<1739, 256, 0, stream>>>(c_bf, WK2t, s1bf, d_bf, WVt, tT_bf, proj, eT_bf, ecum,
                                   bsum_bf);
  k4_step2<<<576, 256, 0, stream>>>(s1bf, bsum_bf, s2bf);
  k5_attn<<<dim3(SEQ, 8), 256, 0, stream>>>(a_bf, s2bf, eT_bf, ecum, ew_bf, Lsum);
  k5b_z<<<dim3(8, 12), 512, 0, stream>>>(ew_bf, tT_bf, Lsum, z_bf);
  k6_out<<<24, 256, 0, stream>>>(z_bf, Wout_bf, b_out, out);
}

// Round 6
// 255.481 us; speedup vs baseline: 1.1790x; 1.1011x over previous
//
#include <hip/hip_runtime.h>
#include <hip/hip_bf16.h>
#include <cstdint>

#define SEQ 192

typedef float f32x4 __attribute__((ext_vector_type(4)));
typedef float f32x8 __attribute__((ext_vector_type(8)));
typedef __bf16 bf16;
typedef __bf16 bf16x8 __attribute__((ext_vector_type(8)));
typedef __bf16 bf16x4 __attribute__((ext_vector_type(4)));

#define MFMA_BF16(a, b, c) __builtin_amdgcn_mfma_f32_16x16x32_bf16(a, b, c, 0, 0, 0)

__device__ __forceinline__ bf16x8 cvt8(f32x8 v) {
  bf16x8 o;
#pragma unroll
  for (int i = 0; i < 8; i++) o[i] = (bf16)v[i];
  return o;
}

// =================== K1: WVt2 transpose + LayerNorm ===================
// WVt2[h][(f*64+g)*64 + h'] = WV[h][h'][g][f]  (so row-major t == consumer layout)
__global__ __launch_bounds__(256) void k1_prep(
    const float* __restrict__ x, const float* __restrict__ ln_w, const float* __restrict__ ln_b,
    const float* __restrict__ WV, bf16* __restrict__ xn_bf, bf16* __restrict__ WVt2) {
  int bid = blockIdx.x, tid = threadIdx.x;
  if (bid < 512) {
    int g = bid & 63, hh = bid >> 6;
    __shared__ float ld[64 * 65];
    int f = tid & 63, r4 = tid >> 6;
#pragma unroll
    for (int it = 0; it < 16; it++) {
      int hp = it * 4 + r4;
      ld[hp * 65 + f] = WV[(((size_t)(hh * 64 + hp) * 64 + g) * 64) + f];
    }
    __syncthreads();
    int hp2 = tid & 63;
#pragma unroll
    for (int it = 0; it < 16; it++) {
      int ff = it * 4 + r4;
      WVt2[(size_t)hh * 262144 + (size_t)(ff * 64 + g) * 64 + hp2] = (bf16)ld[hp2 * 65 + ff];
    }
    return;
  }
  bid -= 512;
  {  // LayerNorm row r = bid
    int r = bid;
    const float* xr = x + (size_t)r * 512;
    float v0 = xr[tid], v1 = xr[tid + 256];
    float s = v0 + v1, s2 = v0 * v0 + v1 * v1;
#pragma unroll
    for (int off = 32; off > 0; off >>= 1) {
      s += __shfl_down(s, off);
      s2 += __shfl_down(s2, off);
    }
    __shared__ float redS[4], redS2[4];
    int wave = tid >> 6, lane = tid & 63;
    if (lane == 0) { redS[wave] = s; redS2[wave] = s2; }
    __syncthreads();
    float S = redS[0] + redS[1] + redS[2] + redS[3];
    float S2 = redS2[0] + redS2[1] + redS2[2] + redS2[3];
    float mean = S * (1.0f / 512.0f);
    float var = S2 * (1.0f / 512.0f) - mean * mean;
    float rstd = rsqrtf(var + 1e-5f);
    bf16* xnr = xn_bf + (size_t)r * 512;
    xnr[tid] = (bf16)((v0 - mean) * rstd * ln_w[tid] + ln_b[tid]);
    xnr[tid + 256] = (bf16)((v1 - mean) * rstd * ln_w[tid + 256] + ln_b[tid + 256]);
  }
}

// =================== LDS-free bf16 MFMA GEMM core (C = A @ Bt^T) ===================
// MODE 1: bf16 row-major ; MODE 2: s2 layout [m>>6][n][m&63] bf16x4
template <int MODE>
__device__ __forceinline__ void gemm_body(const bf16* __restrict__ A, const bf16* __restrict__ Bt,
                                          bf16* __restrict__ C1, int N, int K,
                                          int nb, int mb, int tid) {
  int n0 = nb * 64, m0 = mb * 64;
  int wave = tid >> 6, lane = tid & 63;
  int lq = lane >> 4, l16 = lane & 15;
  const bf16* Ap = A + (size_t)(m0 + wave * 16 + l16) * K;
  f32x4 acc[4];
#pragma unroll
  for (int nt = 0; nt < 4; nt++) acc[nt] = (f32x4){0.f, 0.f, 0.f, 0.f};
  for (int k0 = 0; k0 < K; k0 += 32) {
    bf16x8 af = *(const bf16x8*)(Ap + k0 + lq * 8);
#pragma unroll
    for (int nt = 0; nt < 4; nt++) {
      bf16x8 bv = *(const bf16x8*)(Bt + (size_t)(n0 + nt * 16 + l16) * K + k0 + lq * 8);
      acc[nt] = MFMA_BF16(af, bv, acc[nt]);
    }
  }
  int cm = m0 + wave * 16 + lq * 4;
#pragma unroll
  for (int nt = 0; nt < 4; nt++) {
    int n = n0 + nt * 16 + l16;
    if constexpr (MODE == 1) {
#pragma unroll
      for (int rg = 0; rg < 4; rg++) C1[(size_t)(cm + rg) * N + n] = (bf16)acc[nt][rg];
    } else {
      int r = cm >> 6, i0 = cm & 63;
      bf16x4 pk = {(bf16)acc[nt][0], (bf16)acc[nt][1], (bf16)acc[nt][2], (bf16)acc[nt][3]};
      *(bf16x4*)(C1 + (size_t)r * 12288 + (size_t)n * 64 + i0) = pk;
    }
  }
}

// =================== K2: proj GEMM (inline f32 weight cvt) + slice epilogue ===================
__global__ __launch_bounds__(256) void k2_proj(
    const bf16* __restrict__ xn_bf, const float* __restrict__ Wab,
    const float* __restrict__ b_abcde, float* __restrict__ proj, bf16* __restrict__ a_bf,
    bf16* __restrict__ c_bf, bf16* __restrict__ d_bf) {
  int bid = blockIdx.x, tid = threadIdx.x;
  int nb = bid % 40, mb = bid / 40;
  int n0 = nb * 64, m0 = mb * 64;
  int wave = tid >> 6, lane = tid & 63;
  int lq = lane >> 4, l16 = lane & 15;
  const bf16* Ap = xn_bf + (size_t)(m0 + wave * 16 + l16) * 512;
  f32x4 acc[4];
#pragma unroll
  for (int nt = 0; nt < 4; nt++) acc[nt] = (f32x4){0.f, 0.f, 0.f, 0.f};
  for (int k0 = 0; k0 < 512; k0 += 32) {
    bf16x8 af = *(const bf16x8*)(Ap + k0 + lq * 8);
#pragma unroll
    for (int nt = 0; nt < 4; nt++) {
      f32x8 wv = *(const f32x8*)(Wab + (size_t)(n0 + nt * 16 + l16) * 512 + k0 + lq * 8);
      acc[nt] = MFMA_BF16(af, cvt8(wv), acc[nt]);
    }
  }
  int cm = m0 + wave * 16 + lq * 4;
#pragma unroll
  for (int nt = 0; nt < 4; nt++) {
    int n = n0 + nt * 16 + l16;
    int chunk = n >> 9, hcol = (n >> 6) & 7, i = n & 63;
#pragma unroll
    for (int rg = 0; rg < 4; rg++) {
      int m = cm + rg;
      float v = acc[nt][rg] + b_abcde[n];
      proj[(size_t)m * 2560 + n] = v;
      bf16 bv = (bf16)v;
      if (chunk == 0) a_bf[((size_t)hcol * SEQ + m) * 64 + i] = bv;
      else if (chunk == 2) c_bf[(size_t)m * 512 + (n - 1024)] = bv;
      else if (chunk == 3) d_bf[((size_t)hcol * SEQ + m) * 64 + i] = bv;
    }
  }
}

// =================== K3: step1 GEMM (inline WK cvt) + t GEMM + eT/ecum + bsum ===================
__global__ __launch_bounds__(256) void k3_mid(
    const bf16* __restrict__ c_bf, const float* __restrict__ WK, bf16* __restrict__ s1bf,
    const bf16* __restrict__ d_bf, const bf16* __restrict__ WVt2, bf16* __restrict__ tTt,
    const float* __restrict__ proj, bf16* __restrict__ eT_bf, float* __restrict__ ecum,
    bf16* __restrict__ bsum_bf) {
  __shared__ float el[64 * 65];
  int bid = blockIdx.x, tid = threadIdx.x;
  if (bid < 192) {  // step1: [192 x 4096] = c @ WK2t^T, K=512, B read from WK f32 directly
    int nb = bid % 64, mb = bid / 64;
    int n0 = nb * 64, m0 = mb * 64;
    int wave = tid >> 6, lane = tid & 63;
    int lq = lane >> 4, l16 = lane & 15;
    const bf16* Ap = c_bf + (size_t)(m0 + wave * 16 + l16) * 512;
    f32x4 acc[4];
#pragma unroll
    for (int nt = 0; nt < 4; nt++) acc[nt] = (f32x4){0.f, 0.f, 0.f, 0.f};
    size_t offn[4];
#pragma unroll
    for (int nt = 0; nt < 4; nt++) {
      int n = n0 + nt * 16 + l16;  // n = i*64 + j
      offn[nt] = (size_t)(n >> 6) * 4096 + (size_t)(n & 63) * 64;
    }
    for (int k0 = 0; k0 < 512; k0 += 32) {
      bf16x8 af = *(const bf16x8*)(Ap + k0 + lq * 8);
      size_t kb = (size_t)(k0 >> 6) * 262144 + (k0 & 32) + lq * 8;
#pragma unroll
      for (int nt = 0; nt < 4; nt++) {
        f32x8 wv = *(const f32x8*)(WK + kb + offn[nt]);
        acc[nt] = MFMA_BF16(af, cvt8(wv), acc[nt]);
      }
    }
    int cm = m0 + wave * 16 + lq * 4;
#pragma unroll
    for (int nt = 0; nt < 4; nt++) {
      int n = n0 + nt * 16 + l16;
#pragma unroll
      for (int rg = 0; rg < 4; rg++) s1bf[(size_t)(cm + rg) * 4096 + n] = (bf16)acc[nt][rg];
    }
    return;
  }
  bid -= 192;
  if (bid < 1536) {  // t[h]: [192 x 4096] = d_h @ WVt2[h]^T, K=64 -> row-major == tTt layout
    int h = bid / 192, rem = bid % 192;
    gemm_body<1>(d_bf + (size_t)h * 12288, WVt2 + (size_t)h * 262144,
                 tTt + (size_t)h * 786432, 4096, 64, rem % 64, rem / 64, tid);
    return;
  }
  bid -= 1536;
  if (bid < 8) {  // per-head: eT transpose + ecum prefix scan, 64-row chunks with carry
    int h = bid;
    float carry = 0.f;
    for (int ch = 0; ch < 3; ch++) {
      int pbase = ch * 64;
      for (int idx = tid; idx < 4096; idx += 256) {
        int pl = idx >> 6, g = idx & 63;
        el[pl * 65 + g] = proj[(size_t)(pbase + pl) * 2560 + 2048 + h * 64 + g];
      }
      __syncthreads();
      for (int idx = tid; idx < 4096; idx += 256) {
        int g = idx >> 6, ql = idx & 63;
        eT_bf[((size_t)h * 64 + g) * SEQ + pbase + ql] = (bf16)el[ql * 65 + g];
      }
      if (tid < 64) {
        float run = carry;
        for (int pl = 0; pl < 64; pl++) {
          run += el[pl * 65 + tid];
          ecum[(size_t)h * 12288 + (pbase + pl) * 64 + tid] = run;
        }
        carry = run;
      }
      __syncthreads();
    }
    return;
  }
  bid -= 8;
  {  // bsum[q][j] = sum_h b[q,h,j] -> bf16 ; 3 blocks x 64 q
    int j = tid & 63, qg = tid >> 6;
#pragma unroll
    for (int qi = 0; qi < 16; qi++) {
      int q = bid * 64 + qg * 16 + qi;
      float s = 0.f;
#pragma unroll
      for (int hh = 0; hh < 8; hh++) s += proj[(size_t)q * 2560 + 512 + hh * 64 + j];
      bsum_bf[q * 64 + j] = (bf16)s;
    }
  }
}

// =================== K4: step2 GEMM -> s2bf[r][q][i] ===================
__global__ __launch_bounds__(256) void k4_step2(const bf16* __restrict__ s1bf,
                                                const bf16* __restrict__ bsum_bf,
                                                bf16* __restrict__ s2bf) {
  int bid = blockIdx.x;
  gemm_body<2>(s1bf, bsum_bf, s2bf, 192, 64, bid % 3, bid / 3, threadIdx.x);
}

// =================== K5: scores+exp+ew(+ecum) per (r,h), small-LDS ===================
__global__ __launch_bounds__(256) void k5_attn(
    const bf16* __restrict__ a_bf, const bf16* __restrict__ s2bf,
    const bf16* __restrict__ eT_bf, const float* __restrict__ ecum,
    bf16* __restrict__ ew_bf, float* __restrict__ Lsum) {
  int r = blockIdx.x, h = blockIdx.y;
  int tid = threadIdx.x, wave = tid >> 6, lane = tid & 63;
  int lq = lane >> 4, l16 = lane & 15;
  __shared__ __align__(16) bf16 wch[4][16 * 40];
  __shared__ float redL[4];
  int pt[3] = {wave, wave + 4, 11 - wave};

  const bf16* ah = a_bf + (size_t)h * 12288;
  const bf16* s2r = s2bf + (size_t)r * 12288;
  const bf16* eh = eT_bf + (size_t)h * 12288;
  const float* ech = ecum + (size_t)h * 12288;
  bf16* myw = &wch[wave][0];

  bf16x8 afr[3][2];
#pragma unroll
  for (int mt = 0; mt < 3; mt++)
#pragma unroll
    for (int kc = 0; kc < 2; kc++)
      afr[mt][kc] = *(const bf16x8*)(ah + (pt[mt] * 16 + l16) * 64 + kc * 32 + lq * 8);

  f32x4 ewacc[3][4];
#pragma unroll
  for (int mt = 0; mt < 3; mt++)
#pragma unroll
    for (int nt = 0; nt < 4; nt++) ewacc[mt][nt] = (f32x4){0.f, 0.f, 0.f, 0.f};
  float lpart = 0.f;

  for (int c = 0; c < 6; c++) {
    if (c * 32 + 31 <= wave * 16) continue;
    bf16x8 efr[4];
#pragma unroll
    for (int nt = 0; nt < 4; nt++)
      efr[nt] = *(const bf16x8*)(eh + (nt * 16 + l16) * SEQ + c * 32 + lq * 8);
    bf16x8 bq0[2], bq1[2];
#pragma unroll
    for (int sub = 0; sub < 2; sub++) {
      int q = c * 32 + sub * 16 + l16;
      bq0[sub] = *(const bf16x8*)(s2r + q * 64 + lq * 8);
      bq1[sub] = *(const bf16x8*)(s2r + q * 64 + 32 + lq * 8);
    }
#pragma unroll
    for (int mt = 0; mt < 3; mt++) {
      int ptile = pt[mt];
      if (c * 32 + 31 <= ptile * 16) continue;
#pragma unroll
      for (int sub = 0; sub < 2; sub++) {
        if (c * 32 + sub * 16 + 15 <= ptile * 16) {
#pragma unroll
          for (int rg = 0; rg < 4; rg++) myw[(lq * 4 + rg) * 40 + sub * 16 + l16] = (bf16)0.f;
          continue;
        }
        f32x4 sv = (f32x4){0.f, 0.f, 0.f, 0.f};
        sv = MFMA_BF16(afr[mt][0], bq0[sub], sv);
        sv = MFMA_BF16(afr[mt][1], bq1[sub], sv);
        int q = c * 32 + sub * 16 + l16;
        int p0 = ptile * 16 + lq * 4;
#pragma unroll
        for (int rg = 0; rg < 4; rg++) {
          float wv = (q > p0 + rg) ? __expf(sv[rg] * 0.015625f) : 0.f;
          lpart += wv;
          myw[(lq * 4 + rg) * 40 + sub * 16 + l16] = (bf16)wv;
        }
      }
      bf16x8 wf = *(const bf16x8*)(myw + l16 * 40 + lq * 8);
#pragma unroll
      for (int nt = 0; nt < 4; nt++) ewacc[mt][nt] = MFMA_BF16(wf, efr[nt], ewacc[mt][nt]);
    }
  }

  bf16* ewout = ew_bf + ((size_t)h * SEQ + r) * 12288;
#pragma unroll
  for (int mt = 0; mt < 3; mt++)
#pragma unroll
    for (int nt = 0; nt < 4; nt++)
#pragma unroll
      for (int rg = 0; rg < 4; rg++) {
        int p = pt[mt] * 16 + lq * 4 + rg;
        int g = nt * 16 + l16;
        ewout[p * 64 + g] = (bf16)(ewacc[mt][nt][rg] + ech[p * 64 + g]);
      }

#pragma unroll
  for (int off = 32; off > 0; off >>= 1) lpart += __shfl_down(lpart, off);
  if (lane == 0) redL[wave] = lpart;
  __syncthreads();
  if (tid == 0) Lsum[h * SEQ + r] = redL[0] + redL[1] + redL[2] + redL[3];
}

// =================== K5b: Zpart[ks][r][h*64+f] = ew'[h,r,kslice] @ tTt[h,kslice] ===================
// grid (8 h, 12 mt, 4 ks); 512 thr = 8 waves; k = p*64+g; tTt[h][p][f*64+g].
__global__ __launch_bounds__(512) void k5b_z(
    const bf16* __restrict__ ew_bf, const bf16* __restrict__ tTt, float* __restrict__ Zpart) {
  int h = blockIdx.x, mt = blockIdx.y, ks = blockIdx.z;
  int tid = threadIdx.x, wave = tid >> 6, lane = tid & 63;
  int lq = lane >> 4, l16 = lane & 15;
  __shared__ float zred[8][16][66];
  const bf16* ewh = ew_bf + ((size_t)h * SEQ + mt * 16) * 12288;
  const bf16* th = tTt + (size_t)h * 786432;
  f32x4 acc[4];
#pragma unroll
  for (int nt = 0; nt < 4; nt++) acc[nt] = (f32x4){0.f, 0.f, 0.f, 0.f};
  for (int jj = 0; jj < 12; jj++) {
    int kc = ks * 96 + wave * 12 + jj;   // 32-wide k chunk
    int p = kc >> 1, g0 = (kc & 1) * 32;
    bf16x8 af = *(const bf16x8*)(ewh + (size_t)l16 * 12288 + kc * 32 + lq * 8);
#pragma unroll
    for (int nt = 0; nt < 4; nt++) {
      bf16x8 tf = *(const bf16x8*)(th + (size_t)p * 4096 + (nt * 16 + l16) * 64 + g0 + lq * 8);
      acc[nt] = MFMA_BF16(af, tf, acc[nt]);
    }
  }
#pragma unroll
  for (int nt = 0; nt < 4; nt++)
#pragma unroll
    for (int rg = 0; rg < 4; rg++) zred[wave][lq * 4 + rg][nt * 16 + l16] = acc[nt][rg];
  __syncthreads();
#pragma unroll
  for (int o = 0; o < 2; o++) {
    int idx = o * 512 + tid;  // 1024 outputs: [rloc 16][f 64]
    int rloc = idx >> 6, f = idx & 63;
    float s = 0.f;
#pragma unroll
    for (int wv = 0; wv < 8; wv++) s += zred[wv][rloc][f];
    Zpart[(size_t)ks * 98304 + (size_t)(mt * 16 + rloc) * 512 + h * 64 + f] = s;
  }
}

// =================== K6: out = z @ Wout^T + b_out; z built inline from Zpart/Lsum ===================
__global__ __launch_bounds__(256) void k6_out(
    const float* __restrict__ Zpart, const float* __restrict__ Lsum,
    const float* __restrict__ Wout, const float* __restrict__ b_out, float* __restrict__ out) {
  int bid = blockIdx.x, tid = threadIdx.x;
  int nb = bid & 7, mb = bid >> 3;
  int n0 = nb * 64, m0 = mb * 64;
  int wave = tid >> 6, lane = tid & 63;
  int lq = lane >> 4, l16 = lane & 15;
  int m = m0 + wave * 16 + l16;
  f32x4 acc[4];
#pragma unroll
  for (int nt = 0; nt < 4; nt++) acc[nt] = (f32x4){0.f, 0.f, 0.f, 0.f};
  for (int k0 = 0; k0 < 512; k0 += 32) {
    int h = k0 >> 6;
    float L = Lsum[h * SEQ + m] + 18528.0f;  // 18528 masked (p>=q) entries, weight exactly 1.0f
    float rL = 1.0f / L;
    size_t zo = (size_t)m * 512 + k0 + lq * 8;
    f32x8 s = *(const f32x8*)(Zpart + zo);
    s += *(const f32x8*)(Zpart + 98304 + zo);
    s += *(const f32x8*)(Zpart + 196608 + zo);
    s += *(const f32x8*)(Zpart + 294912 + zo);
    bf16x8 af = cvt8(s * rL);
#pragma unroll
    for (int nt = 0; nt < 4; nt++) {
      f32x8 wv = *(const f32x8*)(Wout + (size_t)(n0 + nt * 16 + l16) * 512 + k0 + lq * 8);
      acc[nt] = MFMA_BF16(af, cvt8(wv), acc[nt]);
    }
  }
  int cm = m0 + wave * 16 + lq * 4;
#pragma unroll
  for (int nt = 0; nt < 4; nt++) {
    int n = n0 + nt * 16 + l16;
    float bv = b_out[n];
#pragma unroll
    for (int rg = 0; rg < 4; rg++) out[(size_t)(cm + rg) * 512 + n] = acc[nt][rg] + bv;
  }
}

// =================== workspace layout (f32 units) ===================
static const size_t OFF_PROJ = 0;         // f32 491520
static const size_t OFF_ECUM = 491520;    // f32 98304
static const size_t OFF_XN = 589824;      // bf16 -> 49152
static const size_t OFF_ZPART = 638976;   // f32 393216
static const size_t OFF_LSUM = 1032192;   // f32 1536
static const size_t OFF_WVT = 2473984;    // bf16 -> 1048576
static const size_t OFF_A = 3522560;      // bf16 -> 49152
static const size_t OFF_C = 3571712;      // 49152
static const size_t OFF_D = 3620864;      // 49152
static const size_t OFF_ET = 3670016;     // 49152
static const size_t OFF_BSUM = 3719168;   // 6144
static const size_t OFF_S1 = 3725312;     // bf16 -> 393216
static const size_t OFF_S2 = 4118528;     // bf16 -> 1179648
static const size_t OFF_TT = 5298176;     // bf16 -> 3145728
static const size_t OFF_EW = 8493056;     // bf16 -> 9437184
// TOTAL = 17930240 f32 = 71.7 MB (same footprint as R5)

extern "C" void kernel_launch(void* const* d_in, const int* in_sizes, int n_in,
                              void* d_out, int out_size, void* d_ws, size_t ws_size,
                              hipStream_t stream) {
  (void)in_sizes; (void)n_in; (void)out_size; (void)ws_size;
  const float* x = (const float*)d_in[0];
  const float* ln_w = (const float*)d_in[1];
  const float* ln_b = (const float*)d_in[2];
  const float* W_abcde = (const float*)d_in[3];
  const float* b_abcde = (const float*)d_in[4];
  const float* W_K = (const float*)d_in[5];
  const float* W_V = (const float*)d_in[6];
  const float* W_out = (const float*)d_in[7];
  const float* b_out = (const float*)d_in[8];
  float* out = (float*)d_out;
  float* ws = (float*)d_ws;

  float* proj = ws + OFF_PROJ;
  float* ecum = ws + OFF_ECUM;
  bf16* xn_bf = (bf16*)(ws + OFF_XN);
  float* Zpart = ws + OFF_ZPART;
  float* Lsum = ws + OFF_LSUM;
  bf16* WVt2 = (bf16*)(ws + OFF_WVT);
  bf16* a_bf = (bf16*)(ws + OFF_A);
  bf16* c_bf = (bf16*)(ws + OFF_C);
  bf16* d_bf = (bf16*)(ws + OFF_D);
  bf16* eT_bf = (bf16*)(ws + OFF_ET);
  bf16* bsum_bf = (bf16*)(ws + OFF_BSUM);
  bf16* s1bf = (bf16*)(ws + OFF_S1);
  bf16* s2bf = (bf16*)(ws + OFF_S2);
  bf16* tTt = (bf16*)(ws + OFF_TT);
  bf16* ew_bf = (bf16*)(ws + OFF_EW);

  k1_prep<<<704, 256, 0, stream>>>(x, ln_w, ln_b, W_V, xn_bf, WVt2);
  k2_proj<<<120, 256, 0, stream>>>(xn_bf, W_abcde, b_abcde, proj, a_bf, c_bf, d_bf);
  k3_mid<<<1739, 256, 0, stream>>>(c_bf, W_K, s1bf, d_bf, WVt2, tTt, proj, eT_bf, ecum,
                                   bsum_bf);
  k4_step2<<<576, 256, 0, stream>>>(s1bf, bsum_bf, s2bf);
  k5_attn<<<dim3(SEQ, 8), 256, 0, stream>>>(a_bf, s2bf, eT_bf, ecum, ew_bf, Lsum);
  k5b_z<<<dim3(8, 12, 4), 512, 0, stream>>>(ew_bf, tTt, Zpart);
  k6_out<<<24, 256, 0, stream>>>(Zpart, Lsum, W_out, b_out, out);
}